// Round 8
// baseline (420.599 us; speedup 1.0000x reference)
//
#include <hip/hip_runtime.h>
#include <hip/hip_bf16.h>
#include <cstdint>
#include <cstddef>

// Problem constants
#define BB   2
#define SS   2048
#define DD   2048
#define HH   16
#define HDD  128
#define SEC  8388608   // B*H*S*HD elements per Q/K/V section
#define NKT  32        // K-tiles of 64 in DD=2048

typedef unsigned short u16;
typedef __attribute__((ext_vector_type(8))) short short8;   // 8 x bf16 (4 VGPRs)
typedef __attribute__((ext_vector_type(4))) float f32x4;    // MFMA 16x16 accumulator

__device__ __forceinline__ u16 f2bf(float f) {
  union { float f; uint32_t u; } v; v.f = f;
  uint32_t r = v.u + 0x7fffu + ((v.u >> 16) & 1u);  // RNE
  return (u16)(r >> 16);
}
__device__ __forceinline__ float bf2f(u16 b) {
  union { uint32_t u; float f; } v; v.u = ((uint32_t)b) << 16;
  return v.f;
}

// async global->LDS, 16B per lane; LDS dest = wave-uniform base + lane*16
__device__ __forceinline__ void gload16(const u16* g, u16* l) {
  __builtin_amdgcn_global_load_lds(
      (__attribute__((address_space(1))) void*)g,
      (__attribute__((address_space(3))) void*)l, 16, 0, 0);
}

// ------- prep: x fp32->bf16 (z>=4) + 4x weight transpose+convert (z<4) -----
__global__ void k_prep(const float* __restrict__ x,
                       const float* __restrict__ w0, const float* __restrict__ w1,
                       const float* __restrict__ w2, const float* __restrict__ w3,
                       u16* __restrict__ xb, u16* __restrict__ wt) {
  const int z = blockIdx.z;
  const int t = threadIdx.y * 32 + threadIdx.x;
  if (z >= 4) {  // convert x
    const int id = (z - 4) * 1024 + blockIdx.y * 32 + blockIdx.x;
    const size_t base = ((size_t)id * 256 + t) * 2;   // float4 units
    const float4* xv = reinterpret_cast<const float4*>(x);
    uint2* ov = reinterpret_cast<uint2*>(xb);
#pragma unroll
    for (int u = 0; u < 2; ++u) {
      const float4 v = xv[base + u];
      uint2 p;
      p.x = (uint32_t)f2bf(v.x) | ((uint32_t)f2bf(v.y) << 16);
      p.y = (uint32_t)f2bf(v.z) | ((uint32_t)f2bf(v.w) << 16);
      ov[base + u] = p;
    }
    return;
  }
  __shared__ float tls[64][65];
  const float* w = (z == 0) ? w0 : (z == 1) ? w1 : (z == 2) ? w2 : w3;
  u16* o = wt + (size_t)z * (DD * DD);
  const int n0 = blockIdx.x * 64, k0 = blockIdx.y * 64;
#pragma unroll
  for (int i = 0; i < 4; ++i) {
    const int f = t + 256 * i;            // float4 index in tile
    const int row = f >> 4, c4 = (f & 15) << 2;
    const float4 v = *reinterpret_cast<const float4*>(
        w + (size_t)(k0 + row) * DD + n0 + c4);
    tls[row][c4 + 0] = v.x; tls[row][c4 + 1] = v.y;
    tls[row][c4 + 2] = v.z; tls[row][c4 + 3] = v.w;
  }
  __syncthreads();
#pragma unroll
  for (int i = 0; i < 2; ++i) {
    const int nrow = (t >> 3) + 32 * i;
    const int kc8 = (t & 7) << 3;
    uint32_t pk[4];
#pragma unroll
    for (int jj = 0; jj < 4; ++jj) {
      const uint32_t lo = f2bf(tls[kc8 + 2 * jj][nrow]);
      const uint32_t hi = f2bf(tls[kc8 + 2 * jj + 1][nrow]);
      pk[jj] = lo | (hi << 16);
    }
    *reinterpret_cast<uint4*>(o + (size_t)(n0 + nrow) * DD + k0 + kc8) =
        make_uint4(pk[0], pk[1], pk[2], pk[3]);
  }
}

// ------- fused QKV GEMM: 256x256 tile, 4-phase/K-tile (T2+T4+T5) -----------
// R2 version (best measured: 133us, MfmaUtil 32, zero bank conflicts).
__global__ __launch_bounds__(512, 2) void k_qkv(const u16* __restrict__ A,
                                                const u16* __restrict__ Bt,
                                                u16* __restrict__ out,
                                                const float* __restrict__ fc,
                                                const float* __restrict__ fs) {
  __shared__ __align__(16) u16 As[2][2][128 * 64];
  __shared__ __align__(16) u16 Bs[2][2][128 * 64];
  const int tid = threadIdx.x;
  const int wave = tid >> 6, lane = tid & 63;
  const int c = lane & 15, g = lane >> 4;
  const int wm = wave >> 2, wn = wave & 3;
  const int x7 = c & 7;
  // XCD-aware swizzle (384 % 8 == 0 -> simple form is bijective)
  const int lb = blockIdx.x;
  const int wg = (lb & 7) * 48 + (lb >> 3);
  const int bx = wg / 24, by = wg % 24;
  const int row0 = bx * 256, col0 = by * 256;
  const int lr3 = lane >> 3;
  const int kch = ((lane & 7) ^ lr3) << 3;

  auto stgA = [&](int t, int h) {
    u16* dst = &As[t & 1][h][0];
#pragma unroll
    for (int u = 0; u < 2; ++u)
      gload16(A + (size_t)(row0 + u * 128 + h * 64 + wave * 8 + lr3) * DD + t * 64 + kch,
              dst + (u * 64 + wave * 8) * 64);
  };
  auto stgB = [&](int t, int h) {
    u16* dst = &Bs[t & 1][h][0];
#pragma unroll
    for (int u = 0; u < 2; ++u)
      gload16(Bt + (size_t)(col0 + u * 128 + wm * 64 + h * 32 + wn * 8 + lr3) * DD + t * 64 + kch,
              dst + (u * 64 + wave * 8) * 64);
  };
  auto rdA = [&](const u16* bp, int ip, int ks) {
    return *reinterpret_cast<const short8*>(
        bp + (wm * 64 + ip * 16 + c) * 64 + ((((ks << 2) | g) ^ x7) << 3));
  };
  auto rdB = [&](const u16* bp, int jp, int ks) {
    return *reinterpret_cast<const short8*>(
        bp + (wn * 32 + jp * 16 + c) * 64 + ((((ks << 2) | g) ^ x7) << 3));
  };

  f32x4 acc[8][4] = {};
  auto quad = [&](short8 (&af)[4][2], short8 (&bf)[2][2], int io, int jo) {
    __builtin_amdgcn_s_setprio(1);
#pragma unroll
    for (int ks = 0; ks < 2; ++ks)
#pragma unroll
      for (int ip = 0; ip < 4; ++ip)
#pragma unroll
        for (int jp = 0; jp < 2; ++jp)
          acc[io + ip][jo + jp] = __builtin_amdgcn_mfma_f32_16x16x32_bf16(
              af[ip][ks], bf[jp][ks], acc[io + ip][jo + jp], 0, 0, 0);
    __builtin_amdgcn_s_setprio(0);
  };
  auto bar = [&]() {
    asm volatile("" ::: "memory");
    __builtin_amdgcn_s_barrier();
    asm volatile("" ::: "memory");
  };

  // prologue: stage tiles 0 and 1 (8 vmem instr each), land tile 0
  stgA(0, 0); stgB(0, 0); stgB(0, 1); stgA(0, 1);
  stgA(1, 0); stgB(1, 0); stgB(1, 1); stgA(1, 1);
  asm volatile("s_waitcnt vmcnt(8)" ::: "memory");
  bar();

  short8 a[4][2], b0[2][2], b1[2][2];
  for (int t = 0; t < NKT; ++t) {
    const u16* A0p = &As[t & 1][0][0];
    const u16* A1p = &As[t & 1][1][0];
    const u16* B0p = &Bs[t & 1][0][0];
    const u16* B1p = &Bs[t & 1][1][0];
    const bool pf = (t + 2 < NKT);
    // ---- phase 1 (0,0): 12 ds_reads, no stage
#pragma unroll
    for (int ip = 0; ip < 4; ++ip)
#pragma unroll
      for (int ks = 0; ks < 2; ++ks)
        a[ip][ks] = rdA(A0p, ip, ks);
#pragma unroll
    for (int jp = 0; jp < 2; ++jp)
#pragma unroll
      for (int ks = 0; ks < 2; ++ks)
        b0[jp][ks] = rdB(B0p, jp, ks);
    quad(a, b0, 0, 0);
    bar();
    // ---- phase 2 (0,1): 4 ds_reads, stage A0/B0 of t+2 (dead since ph1)
#pragma unroll
    for (int jp = 0; jp < 2; ++jp)
#pragma unroll
      for (int ks = 0; ks < 2; ++ks)
        b1[jp][ks] = rdB(B1p, jp, ks);
    if (pf) { stgA(t + 2, 0); stgB(t + 2, 0); }
    quad(a, b1, 0, 2);
    bar();
    // ---- phase 3 (1,0): 8 ds_reads, stage B1 of t+2 (dead since ph2)
#pragma unroll
    for (int ip = 0; ip < 4; ++ip)
#pragma unroll
      for (int ks = 0; ks < 2; ++ks)
        a[ip][ks] = rdA(A1p, ip, ks);
    if (pf) stgB(t + 2, 1);
    quad(a, b0, 4, 0);
    bar();
    // ---- phase 4 (1,1): 0 ds_reads, stage A1 of t+2 (dead since ph3)
    if (pf) stgA(t + 2, 1);
    if (t < NKT - 2)
      asm volatile("s_waitcnt vmcnt(8)" ::: "memory");
    else if (t == NKT - 2)
      asm volatile("s_waitcnt vmcnt(0)" ::: "memory");
    quad(a, b1, 4, 2);
    bar();
  }

  // epilogue: D layout col=lane&15, row=(lane>>4)*4+reg (m89-verified)
  const int which = col0 >> 11;                    // block-uniform: 0=Q,1=K,2=V
#pragma unroll
  for (int i = 0; i < 8; ++i) {
    const int mb = row0 + wm * 128 + i * 16 + g * 4;
    const int b_ = mb >> 11, s0_ = mb & (SS - 1);
#pragma unroll
    for (int j = 0; j < 4; ++j) {
      const int n = col0 + wn * 64 + j * 16 + c;
      const int h_ = (n >> 7) & 15, d_ = n & (HDD - 1);
      if (which == 2) {
        ushort4 pk;
        pk.x = f2bf(acc[i][j][0]); pk.y = f2bf(acc[i][j][1]);
        pk.z = f2bf(acc[i][j][2]); pk.w = f2bf(acc[i][j][3]);
        *reinterpret_cast<ushort4*>(
            out + 2 * (size_t)SEC + (((size_t)(b_ * HH + h_)) * HDD + d_) * SS + s0_) = pk;
      } else {
        const int p = d_ >> 1;
        const bool ev = (d_ & 1) == 0;
        const float qsc = (which == 0) ? 0.08838834764831845f : 1.0f;
#pragma unroll
        for (int r = 0; r < 4; ++r) {
          const int s_ = s0_ + r;
          const float own = acc[i][j][r];
          const float par = __shfl_xor(own, 1);
          const float cv = fc[s_ * 64 + p], sv = fs[s_ * 64 + p];
          const float ro = ev ? (own * cv - par * sv) : (par * sv + own * cv);
          out[(size_t)which * SEC + (((size_t)(b_ * HH + h_)) * SS + s_) * HDD + d_] =
              f2bf(ro * qsc);
        }
      }
    }
  }
}

// ------- output projection, split-K: 256x256 tile x K/2, 4-phase -----------
// R8: out-proj at N=2048 was 105us / 330 TF under the m97 structure (best
// of 3 tried structures; big-tile 4-phase would give only 128 blocks).
// Split-K fixes the geometry: grid 16x8x2 = 256 blocks = exactly 1 dispatch
// wave, each block runs the PROVEN k_qkv 4-phase schedule over K/2
// (NKT2=16), writing fp32 partials; k_red sums them. Deterministic.
// Partials alias dead workspace (p0 = Qb..Kb, p1 = xb..wqt; both dead by
// the time this kernel runs in stream order).
#define NKT2 16
__global__ __launch_bounds__(512, 2) void k_outp(const u16* __restrict__ A,
                                                 const u16* __restrict__ Bt,
                                                 float* __restrict__ p0,
                                                 float* __restrict__ p1) {
  __shared__ __align__(16) u16 As[2][2][128 * 64];
  __shared__ __align__(16) u16 Bs[2][2][128 * 64];
  const int tid = threadIdx.x;
  const int wave = tid >> 6, lane = tid & 63;
  const int c = lane & 15, g = lane >> 4;
  const int wm = wave >> 2, wn = wave & 3;
  const int x7 = c & 7;
  // XCD-aware swizzle (256 % 8 == 0 -> bijective)
  const int lb = blockIdx.x;
  const int wg = (lb & 7) * 32 + (lb >> 3);
  const int bx = wg >> 4;               // 0..15 -> row tile
  const int by = (wg >> 1) & 7;         // 0..7  -> col tile
  const int ks_ = wg & 1;               // 0/1   -> K half
  const int row0 = bx * 256, col0 = by * 256;
  const int kb0 = ks_ * (DD / 2);       // K base
  float* part = ks_ ? p1 : p0;
  const int lr3 = lane >> 3;
  const int kch = ((lane & 7) ^ lr3) << 3;

  auto stgA = [&](int t, int h) {
    u16* dst = &As[t & 1][h][0];
#pragma unroll
    for (int u = 0; u < 2; ++u)
      gload16(A + (size_t)(row0 + u * 128 + h * 64 + wave * 8 + lr3) * DD + kb0 + t * 64 + kch,
              dst + (u * 64 + wave * 8) * 64);
  };
  auto stgB = [&](int t, int h) {
    u16* dst = &Bs[t & 1][h][0];
#pragma unroll
    for (int u = 0; u < 2; ++u)
      gload16(Bt + (size_t)(col0 + u * 128 + wm * 64 + h * 32 + wn * 8 + lr3) * DD + kb0 + t * 64 + kch,
              dst + (u * 64 + wave * 8) * 64);
  };
  auto rdA = [&](const u16* bp, int ip, int ks) {
    return *reinterpret_cast<const short8*>(
        bp + (wm * 64 + ip * 16 + c) * 64 + ((((ks << 2) | g) ^ x7) << 3));
  };
  auto rdB = [&](const u16* bp, int jp, int ks) {
    return *reinterpret_cast<const short8*>(
        bp + (wn * 32 + jp * 16 + c) * 64 + ((((ks << 2) | g) ^ x7) << 3));
  };

  f32x4 acc[8][4] = {};
  auto quad = [&](short8 (&af)[4][2], short8 (&bf)[2][2], int io, int jo) {
    __builtin_amdgcn_s_setprio(1);
#pragma unroll
    for (int ks = 0; ks < 2; ++ks)
#pragma unroll
      for (int ip = 0; ip < 4; ++ip)
#pragma unroll
        for (int jp = 0; jp < 2; ++jp)
          acc[io + ip][jo + jp] = __builtin_amdgcn_mfma_f32_16x16x32_bf16(
              af[ip][ks], bf[jp][ks], acc[io + ip][jo + jp], 0, 0, 0);
    __builtin_amdgcn_s_setprio(0);
  };
  auto bar = [&]() {
    asm volatile("" ::: "memory");
    __builtin_amdgcn_s_barrier();
    asm volatile("" ::: "memory");
  };

  stgA(0, 0); stgB(0, 0); stgB(0, 1); stgA(0, 1);
  stgA(1, 0); stgB(1, 0); stgB(1, 1); stgA(1, 1);
  asm volatile("s_waitcnt vmcnt(8)" ::: "memory");
  bar();

  short8 a[4][2], b0[2][2], b1[2][2];
  for (int t = 0; t < NKT2; ++t) {
    const u16* A0p = &As[t & 1][0][0];
    const u16* A1p = &As[t & 1][1][0];
    const u16* B0p = &Bs[t & 1][0][0];
    const u16* B1p = &Bs[t & 1][1][0];
    const bool pf = (t + 2 < NKT2);
#pragma unroll
    for (int ip = 0; ip < 4; ++ip)
#pragma unroll
      for (int ks = 0; ks < 2; ++ks)
        a[ip][ks] = rdA(A0p, ip, ks);
#pragma unroll
    for (int jp = 0; jp < 2; ++jp)
#pragma unroll
      for (int ks = 0; ks < 2; ++ks)
        b0[jp][ks] = rdB(B0p, jp, ks);
    quad(a, b0, 0, 0);
    bar();
#pragma unroll
    for (int jp = 0; jp < 2; ++jp)
#pragma unroll
      for (int ks = 0; ks < 2; ++ks)
        b1[jp][ks] = rdB(B1p, jp, ks);
    if (pf) { stgA(t + 2, 0); stgB(t + 2, 0); }
    quad(a, b1, 0, 2);
    bar();
#pragma unroll
    for (int ip = 0; ip < 4; ++ip)
#pragma unroll
      for (int ks = 0; ks < 2; ++ks)
        a[ip][ks] = rdA(A1p, ip, ks);
    if (pf) stgB(t + 2, 1);
    quad(a, b0, 4, 0);
    bar();
    if (pf) stgA(t + 2, 1);
    if (t < NKT2 - 2)
      asm volatile("s_waitcnt vmcnt(8)" ::: "memory");
    else if (t == NKT2 - 2)
      asm volatile("s_waitcnt vmcnt(0)" ::: "memory");
    quad(a, b1, 4, 2);
    bar();
  }

  // epilogue: plain fp32 partial store
#pragma unroll
  for (int i = 0; i < 8; ++i) {
    const int mb = row0 + wm * 128 + i * 16 + g * 4;
#pragma unroll
    for (int j = 0; j < 4; ++j) {
      const int n = col0 + wn * 64 + j * 16 + c;
#pragma unroll
      for (int r = 0; r < 4; ++r)
        part[(size_t)(mb + r) * DD + n] = acc[i][j][r];
    }
  }
}

// ------- reduce: d_out = p0 + p1 (float4-vectorized) -----------------------
__global__ __launch_bounds__(256) void k_red(const float4* __restrict__ p0,
                                             const float4* __restrict__ p1,
                                             float4* __restrict__ o) {
  const size_t i = ((size_t)blockIdx.x * 256 + threadIdx.x) * 2;
#pragma unroll
  for (int u = 0; u < 2; ++u) {
    const float4 a = p0[i + u], b = p1[i + u];
    o[i + u] = make_float4(a.x + b.x, a.y + b.y, a.z + b.z, a.w + b.w);
  }
}

// ------- causal flash attention (staged, software-pipelined dbuf) ----------
__global__ __launch_bounds__(256, 3) void k_attn(const u16* __restrict__ Q,
                                                 const u16* __restrict__ K,
                                                 const u16* __restrict__ Vt,
                                                 u16* __restrict__ O) {
  __shared__ __align__(16) u16 Kt[2][32 * 128];   // (kv, d) XOR-swizzled chunks
  __shared__ __align__(16) u16 Vs[2][128 * 32];   // (d, kv) XOR-swizzled chunks
  __shared__ __align__(16) u16 Pb[4 * 32 * 40];   // per-wave P (row, kv), stride 40
  const int tid = threadIdx.x;
  const int wave = tid >> 6, lane = tid & 63;
  const int c = lane & 15, g = lane >> 4;
  const int l = blockIdx.x;
  int qi, bh;
  if (l < 256) { qi = 8 + (l & 7); bh = l >> 3; }
  else         { qi = 7 - ((l - 256) & 7); bh = (l - 256) >> 3; }
  const int q0 = qi * 128;
  const u16* Qp = Q  + (size_t)bh * SS * HDD;
  const u16* Kp = K  + (size_t)bh * SS * HDD;
  const u16* Vp = Vt + (size_t)bh * SS * HDD;    // (HD,S)
  short8 qf[2][4];
#pragma unroll
  for (int ms = 0; ms < 2; ++ms)
#pragma unroll
    for (int kd = 0; kd < 4; ++kd)
      qf[ms][kd] = *reinterpret_cast<const short8*>(
          Qp + (size_t)(q0 + wave * 32 + ms * 16 + c) * HDD + kd * 32 + g * 8);
  f32x4 acc[2][8] = {};
  float psum[2][4] = {};
  const int ntiles = (qi + 1) * 4;               // kv tiles of 32 up to q0+128
  u16* pwav = Pb + wave * (32 * 40);
  const int krl = lane >> 4, kcl = lane & 15;    // K: 4 rows/instr, 16 chunks
  const int vrl = lane >> 2, vcl = lane & 3;     // V: 16 rows/instr, 4 chunks
  auto stage = [&](int t) {
    const int kv0 = t * 32;
    u16* kb = Kt[t & 1];
    u16* vb = Vs[t & 1];
#pragma unroll
    for (int j = 0; j < 2; ++j) {
      const int r0k = (j * 4 + wave) * 4;        // rows 0..31, step 4
      const int rowk = r0k + krl;
      gload16(Kp + (size_t)(kv0 + rowk) * HDD + ((kcl ^ (rowk & 15)) << 3),
              kb + r0k * 128);
      const int r0v = (j * 4 + wave) * 16;       // d-rows 0..127, step 16
      const int rowv = r0v + vrl;
      gload16(Vp + (size_t)rowv * SS + kv0 + ((vcl ^ (vrl & 3)) << 3),
              vb + r0v * 32);
    }
  };
  stage(0);
  for (int t = 0; t < ntiles; ++t) {
    __syncthreads();   // drains loads for tile t (issued a full tile ago)
    if (t + 1 < ntiles) stage(t + 1);
    const int kv0 = t * 32;
    const bool active = kv0 <= q0 + wave * 32 + 31;  // wave-uniform
    if (!active) continue;
    const u16* kb = Kt[t & 1];
    const u16* vv = Vs[t & 1];
    f32x4 s[2][2] = {};
#pragma unroll
    for (int ns = 0; ns < 2; ++ns)
#pragma unroll
      for (int kd = 0; kd < 4; ++kd) {
        const short8 b = *reinterpret_cast<const short8*>(
            kb + (ns * 16 + c) * 128 + (((kd * 4 + g) ^ c) << 3));
        s[0][ns] = __builtin_amdgcn_mfma_f32_16x16x32_bf16(qf[0][kd], b, s[0][ns], 0, 0, 0);
        s[1][ns] = __builtin_amdgcn_mfma_f32_16x16x32_bf16(qf[1][kd], b, s[1][ns], 0, 0, 0);
      }
#pragma unroll
    for (int ms = 0; ms < 2; ++ms) {
      const int qrow = q0 + wave * 32 + ms * 16 + g * 4;
#pragma unroll
      for (int r = 0; r < 4; ++r) {
        u16* pw = pwav + (ms * 16 + g * 4 + r) * 40 + c;
        float rs = 0.f;
#pragma unroll
        for (int ns = 0; ns < 2; ++ns) {
          const bool u = (kv0 + ns * 16 + c) <= (qrow + r);
          const float p = u ? __expf(s[ms][ns][r]) : 0.f;
          rs += p;
          pw[ns * 16] = f2bf(p);
        }
        psum[ms][r] += rs;
      }
    }
    short8 pa[2];
    pa[0] = *reinterpret_cast<const short8*>(pwav + c * 40 + g * 8);
    pa[1] = *reinterpret_cast<const short8*>(pwav + (16 + c) * 40 + g * 8);
#pragma unroll
    for (int nb = 0; nb < 8; ++nb) {
      const short8 vb2 = *reinterpret_cast<const short8*>(
          vv + (nb * 16 + c) * 32 + ((g ^ (c & 3)) << 3));
      acc[0][nb] = __builtin_amdgcn_mfma_f32_16x16x32_bf16(pa[0], vb2, acc[0][nb], 0, 0, 0);
      acc[1][nb] = __builtin_amdgcn_mfma_f32_16x16x32_bf16(pa[1], vb2, acc[1][nb], 0, 0, 0);
    }
  }
  const int b_ = bh >> 4, h_ = bh & 15;
#pragma unroll
  for (int ms = 0; ms < 2; ++ms) {
#pragma unroll
    for (int r = 0; r < 4; ++r) {
      float rs = psum[ms][r];
      rs += __shfl_xor(rs, 1);
      rs += __shfl_xor(rs, 2);
      rs += __shfl_xor(rs, 4);
      rs += __shfl_xor(rs, 8);
      const float inv = 1.f / rs;
      const int s_ = q0 + wave * 32 + ms * 16 + g * 4 + r;
      u16* op = O + ((size_t)(b_ * SS + s_)) * DD + h_ * HDD;
#pragma unroll
      for (int nb = 0; nb < 8; ++nb)
        op[nb * 16 + c] = f2bf(acc[ms][nb][r] * inv);
    }
  }
}

extern "C" void kernel_launch(void* const* d_in, const int* in_sizes, int n_in,
                              void* d_out, int out_size, void* d_ws, size_t ws_size,
                              hipStream_t stream) {
  const float* x  = (const float*)d_in[0];
  const float* fc = (const float*)d_in[1];
  const float* fs = (const float*)d_in[2];
  // d_in[3] = mask (unused; causal applied analytically)
  const float* wq = (const float*)d_in[4];
  const float* wk = (const float*)d_in[5];
  const float* wv = (const float*)d_in[6];
  const float* wo = (const float*)d_in[7];

  // workspace layout (bf16 elements)
  u16* ws  = (u16*)d_ws;
  u16* xb  = ws;                  // 4096x2048
  u16* wqt = xb  + 8388608;       // 2048x2048 each (N,K); wq/wk/wv contiguous
  u16* wot = wqt + 3 * 4194304;   // output-proj weight (N,K)
  u16* Qb  = wot + 4194304;       // section 0: Q (B,H,S,HD), RoPE'd+scaled
  u16* Kb  = Qb  + SEC;           // section 1: K (B,H,S,HD), RoPE'd
  u16* Vtb = Kb  + SEC;           // section 2: V transposed (B,H,HD,S)
  u16* ao  = Vtb + SEC;           // (B,S,DIM) attention output
  // split-K fp32 partials alias DEAD regions (stream-order safe):
  // p0 = Qb..Kb (32 MB, dead after k_attn); p1 = xb..wqt (dead after k_qkv)
  float* p0 = (float*)Qb;
  float* p1 = (float*)xb;

  // prep: x conversion (z=4..7) + 4 weight transposes (z=0..3) in one launch
  k_prep<<<dim3(32, 32, 8), dim3(32, 8), 0, stream>>>(x, wq, wk, wv, wo, xb, wqt);
  // fused QKV projection + RoPE epilogue, 256^2 4-phase schedule (R2)
  k_qkv<<<384, 512, 0, stream>>>(xb, wqt, Qb, fc, fs);
  k_attn<<<512, 256, 0, stream>>>(Qb, Kb, Vtb, ao);
  // output projection: split-K 4-phase partials + reduce
  k_outp<<<256, 512, 0, stream>>>(ao, wot, p0, p1);
  k_red<<<4096, 256, 0, stream>>>((const float4*)p0, (const float4*)p1,
                                  (float4*)d_out);
}

// Round 9
// 416.374 us; speedup vs baseline: 1.0101x; 1.0101x over previous
//
#include <hip/hip_runtime.h>
#include <hip/hip_bf16.h>
#include <cstdint>
#include <cstddef>

// Problem constants
#define BB   2
#define SS   2048
#define DD   2048
#define HH   16
#define HDD  128
#define SEC  8388608   // B*H*S*HD elements per Q/K/V section
#define NKT  32        // K-tiles of 64 in DD=2048

typedef unsigned short u16;
typedef __attribute__((ext_vector_type(8))) short short8;   // 8 x bf16 (4 VGPRs)
typedef __attribute__((ext_vector_type(4))) float f32x4;    // MFMA 16x16 accumulator

__device__ __forceinline__ u16 f2bf(float f) {
  union { float f; uint32_t u; } v; v.f = f;
  uint32_t r = v.u + 0x7fffu + ((v.u >> 16) & 1u);  // RNE
  return (u16)(r >> 16);
}
__device__ __forceinline__ float bf2f(u16 b) {
  union { uint32_t u; float f; } v; v.u = ((uint32_t)b) << 16;
  return v.f;
}

// async global->LDS, 16B per lane; LDS dest = wave-uniform base + lane*16
__device__ __forceinline__ void gload16(const u16* g, u16* l) {
  __builtin_amdgcn_global_load_lds(
      (__attribute__((address_space(1))) void*)g,
      (__attribute__((address_space(3))) void*)l, 16, 0, 0);
}

// ------- prep: x fp32->bf16 (z>=4) + 4x weight transpose+convert (z<4) -----
__global__ void k_prep(const float* __restrict__ x,
                       const float* __restrict__ w0, const float* __restrict__ w1,
                       const float* __restrict__ w2, const float* __restrict__ w3,
                       u16* __restrict__ xb, u16* __restrict__ wt) {
  const int z = blockIdx.z;
  const int t = threadIdx.y * 32 + threadIdx.x;
  if (z >= 4) {  // convert x
    const int id = (z - 4) * 1024 + blockIdx.y * 32 + blockIdx.x;
    const size_t base = ((size_t)id * 256 + t) * 2;   // float4 units
    const float4* xv = reinterpret_cast<const float4*>(x);
    uint2* ov = reinterpret_cast<uint2*>(xb);
#pragma unroll
    for (int u = 0; u < 2; ++u) {
      const float4 v = xv[base + u];
      uint2 p;
      p.x = (uint32_t)f2bf(v.x) | ((uint32_t)f2bf(v.y) << 16);
      p.y = (uint32_t)f2bf(v.z) | ((uint32_t)f2bf(v.w) << 16);
      ov[base + u] = p;
    }
    return;
  }
  __shared__ float tls[64][65];
  const float* w = (z == 0) ? w0 : (z == 1) ? w1 : (z == 2) ? w2 : w3;
  u16* o = wt + (size_t)z * (DD * DD);
  const int n0 = blockIdx.x * 64, k0 = blockIdx.y * 64;
#pragma unroll
  for (int i = 0; i < 4; ++i) {
    const int f = t + 256 * i;            // float4 index in tile
    const int row = f >> 4, c4 = (f & 15) << 2;
    const float4 v = *reinterpret_cast<const float4*>(
        w + (size_t)(k0 + row) * DD + n0 + c4);
    tls[row][c4 + 0] = v.x; tls[row][c4 + 1] = v.y;
    tls[row][c4 + 2] = v.z; tls[row][c4 + 3] = v.w;
  }
  __syncthreads();
#pragma unroll
  for (int i = 0; i < 2; ++i) {
    const int nrow = (t >> 3) + 32 * i;
    const int kc8 = (t & 7) << 3;
    uint32_t pk[4];
#pragma unroll
    for (int jj = 0; jj < 4; ++jj) {
      const uint32_t lo = f2bf(tls[kc8 + 2 * jj][nrow]);
      const uint32_t hi = f2bf(tls[kc8 + 2 * jj + 1][nrow]);
      pk[jj] = lo | (hi << 16);
    }
    *reinterpret_cast<uint4*>(o + (size_t)(n0 + nrow) * DD + k0 + kc8) =
        make_uint4(pk[0], pk[1], pk[2], pk[3]);
  }
}

// ------- fused QKV GEMM: 256x256 tile, 4-phase/K-tile (T2+T4+T5) -----------
// R2 version (best measured: 133us, MfmaUtil 32, zero bank conflicts).
// ONE barrier per phase (end); within a phase the 2 waves/SIMD slide.
// Hazard audit: every stage(t+2,R)-vs-read(t,R) pair is separated by >=1
// end-phase barrier; block-wide gload visibility = each wave's vmcnt at
// ph4 + the ph4 end barrier.
__global__ __launch_bounds__(512, 2) void k_qkv(const u16* __restrict__ A,
                                                const u16* __restrict__ Bt,
                                                u16* __restrict__ out,
                                                const float* __restrict__ fc,
                                                const float* __restrict__ fs) {
  __shared__ __align__(16) u16 As[2][2][128 * 64];
  __shared__ __align__(16) u16 Bs[2][2][128 * 64];
  const int tid = threadIdx.x;
  const int wave = tid >> 6, lane = tid & 63;
  const int c = lane & 15, g = lane >> 4;
  const int wm = wave >> 2, wn = wave & 3;
  const int x7 = c & 7;
  // XCD-aware swizzle (384 % 8 == 0 -> simple form is bijective)
  const int lb = blockIdx.x;
  const int wg = (lb & 7) * 48 + (lb >> 3);
  const int bx = wg / 24, by = wg % 24;
  const int row0 = bx * 256, col0 = by * 256;
  const int lr3 = lane >> 3;
  const int kch = ((lane & 7) ^ lr3) << 3;

  auto stgA = [&](int t, int h) {
    u16* dst = &As[t & 1][h][0];
#pragma unroll
    for (int u = 0; u < 2; ++u)
      gload16(A + (size_t)(row0 + u * 128 + h * 64 + wave * 8 + lr3) * DD + t * 64 + kch,
              dst + (u * 64 + wave * 8) * 64);
  };
  auto stgB = [&](int t, int h) {
    u16* dst = &Bs[t & 1][h][0];
#pragma unroll
    for (int u = 0; u < 2; ++u)
      gload16(Bt + (size_t)(col0 + u * 128 + wm * 64 + h * 32 + wn * 8 + lr3) * DD + t * 64 + kch,
              dst + (u * 64 + wave * 8) * 64);
  };
  auto rdA = [&](const u16* bp, int ip, int ks) {
    return *reinterpret_cast<const short8*>(
        bp + (wm * 64 + ip * 16 + c) * 64 + ((((ks << 2) | g) ^ x7) << 3));
  };
  auto rdB = [&](const u16* bp, int jp, int ks) {
    return *reinterpret_cast<const short8*>(
        bp + (wn * 32 + jp * 16 + c) * 64 + ((((ks << 2) | g) ^ x7) << 3));
  };

  f32x4 acc[8][4] = {};
  auto quad = [&](short8 (&af)[4][2], short8 (&bf)[2][2], int io, int jo) {
    __builtin_amdgcn_s_setprio(1);
#pragma unroll
    for (int ks = 0; ks < 2; ++ks)
#pragma unroll
      for (int ip = 0; ip < 4; ++ip)
#pragma unroll
        for (int jp = 0; jp < 2; ++jp)
          acc[io + ip][jo + jp] = __builtin_amdgcn_mfma_f32_16x16x32_bf16(
              af[ip][ks], bf[jp][ks], acc[io + ip][jo + jp], 0, 0, 0);
    __builtin_amdgcn_s_setprio(0);
  };
  auto bar = [&]() {
    asm volatile("" ::: "memory");
    __builtin_amdgcn_s_barrier();
    asm volatile("" ::: "memory");
  };

  // prologue: stage tiles 0 and 1 (8 vmem instr each), land tile 0
  stgA(0, 0); stgB(0, 0); stgB(0, 1); stgA(0, 1);
  stgA(1, 0); stgB(1, 0); stgB(1, 1); stgA(1, 1);
  asm volatile("s_waitcnt vmcnt(8)" ::: "memory");
  bar();

  short8 a[4][2], b0[2][2], b1[2][2];
  for (int t = 0; t < NKT; ++t) {
    const u16* A0p = &As[t & 1][0][0];
    const u16* A1p = &As[t & 1][1][0];
    const u16* B0p = &Bs[t & 1][0][0];
    const u16* B1p = &Bs[t & 1][1][0];
    const bool pf = (t + 2 < NKT);
    // ---- phase 1 (0,0): 12 ds_reads, no stage
#pragma unroll
    for (int ip = 0; ip < 4; ++ip)
#pragma unroll
      for (int ks = 0; ks < 2; ++ks)
        a[ip][ks] = rdA(A0p, ip, ks);
#pragma unroll
    for (int jp = 0; jp < 2; ++jp)
#pragma unroll
      for (int ks = 0; ks < 2; ++ks)
        b0[jp][ks] = rdB(B0p, jp, ks);
    quad(a, b0, 0, 0);
    bar();
    // ---- phase 2 (0,1): 4 ds_reads, stage A0/B0 of t+2 (dead since ph1)
#pragma unroll
    for (int jp = 0; jp < 2; ++jp)
#pragma unroll
      for (int ks = 0; ks < 2; ++ks)
        b1[jp][ks] = rdB(B1p, jp, ks);
    if (pf) { stgA(t + 2, 0); stgB(t + 2, 0); }
    quad(a, b1, 0, 2);
    bar();
    // ---- phase 3 (1,0): 8 ds_reads, stage B1 of t+2 (dead since ph2)
#pragma unroll
    for (int ip = 0; ip < 4; ++ip)
#pragma unroll
      for (int ks = 0; ks < 2; ++ks)
        a[ip][ks] = rdA(A1p, ip, ks);
    if (pf) stgB(t + 2, 1);
    quad(a, b0, 4, 0);
    bar();
    // ---- phase 4 (1,1): 0 ds_reads, stage A1 of t+2 (dead since ph3)
    if (pf) stgA(t + 2, 1);
    if (t < NKT - 2)
      asm volatile("s_waitcnt vmcnt(8)" ::: "memory");
    else if (t == NKT - 2)
      asm volatile("s_waitcnt vmcnt(0)" ::: "memory");
    quad(a, b1, 4, 2);
    bar();
  }

  // epilogue: D layout col=lane&15, row=(lane>>4)*4+reg (m89-verified)
  const int which = col0 >> 11;                    // block-uniform: 0=Q,1=K,2=V
#pragma unroll
  for (int i = 0; i < 8; ++i) {
    const int mb = row0 + wm * 128 + i * 16 + g * 4;
    const int b_ = mb >> 11, s0_ = mb & (SS - 1);
#pragma unroll
    for (int j = 0; j < 4; ++j) {
      const int n = col0 + wn * 64 + j * 16 + c;
      const int h_ = (n >> 7) & 15, d_ = n & (HDD - 1);
      if (which == 2) {
        ushort4 pk;
        pk.x = f2bf(acc[i][j][0]); pk.y = f2bf(acc[i][j][1]);
        pk.z = f2bf(acc[i][j][2]); pk.w = f2bf(acc[i][j][3]);
        *reinterpret_cast<ushort4*>(
            out + 2 * (size_t)SEC + (((size_t)(b_ * HH + h_)) * HDD + d_) * SS + s0_) = pk;
      } else {
        const int p = d_ >> 1;
        const bool ev = (d_ & 1) == 0;
        const float qsc = (which == 0) ? 0.08838834764831845f : 1.0f;
#pragma unroll
        for (int r = 0; r < 4; ++r) {
          const int s_ = s0_ + r;
          const float own = acc[i][j][r];
          const float par = __shfl_xor(own, 1);
          const float cv = fc[s_ * 64 + p], sv = fs[s_ * 64 + p];
          const float ro = ev ? (own * cv - par * sv) : (par * sv + own * cv);
          out[(size_t)which * SEC + (((size_t)(b_ * HH + h_)) * SS + s_) * HDD + d_] =
              f2bf(ro * qsc);
        }
      }
    }
  }
}

// ------- output projection: 256x256 tile, 4-phase (k_qkv clone) ------------
// R9: the proven 4-phase 256^2 schedule runs one 256x256xK2048 block in
// ~89us at 31% pipe eff (measured via k_qkv's stagger: 133us x 256/384).
// m97 small-tile out-proj = 105us at 13% eff. Grid 16x8 = 128 blocks: only
// half the CUs busy, but all 128 run concurrently -> makespan ~= one
// per-block duration ~= 89us < 105. (R4/R8 falsified the "dispatch-wave
// tail" model: blocks backfill, so per-block efficiency is what matters.)
// Identical loop/hazard structure to k_qkv; epilogue = plain fp32 store.
__global__ __launch_bounds__(512, 2) void k_oproj(const u16* __restrict__ A,
                                                  const u16* __restrict__ Bt,
                                                  float* __restrict__ out) {
  __shared__ __align__(16) u16 As[2][2][128 * 64];
  __shared__ __align__(16) u16 Bs[2][2][128 * 64];
  const int tid = threadIdx.x;
  const int wave = tid >> 6, lane = tid & 63;
  const int c = lane & 15, g = lane >> 4;
  const int wm = wave >> 2, wn = wave & 3;
  const int x7 = c & 7;
  // XCD-aware swizzle (128 % 8 == 0 -> bijective)
  const int lb = blockIdx.x;
  const int wg = (lb & 7) * 16 + (lb >> 3);
  const int bx = wg >> 3, by = wg & 7;
  const int row0 = bx * 256, col0 = by * 256;
  const int lr3 = lane >> 3;
  const int kch = ((lane & 7) ^ lr3) << 3;

  auto stgA = [&](int t, int h) {
    u16* dst = &As[t & 1][h][0];
#pragma unroll
    for (int u = 0; u < 2; ++u)
      gload16(A + (size_t)(row0 + u * 128 + h * 64 + wave * 8 + lr3) * DD + t * 64 + kch,
              dst + (u * 64 + wave * 8) * 64);
  };
  auto stgB = [&](int t, int h) {
    u16* dst = &Bs[t & 1][h][0];
#pragma unroll
    for (int u = 0; u < 2; ++u)
      gload16(Bt + (size_t)(col0 + u * 128 + wm * 64 + h * 32 + wn * 8 + lr3) * DD + t * 64 + kch,
              dst + (u * 64 + wave * 8) * 64);
  };
  auto rdA = [&](const u16* bp, int ip, int ks) {
    return *reinterpret_cast<const short8*>(
        bp + (wm * 64 + ip * 16 + c) * 64 + ((((ks << 2) | g) ^ x7) << 3));
  };
  auto rdB = [&](const u16* bp, int jp, int ks) {
    return *reinterpret_cast<const short8*>(
        bp + (wn * 32 + jp * 16 + c) * 64 + ((((ks << 2) | g) ^ x7) << 3));
  };

  f32x4 acc[8][4] = {};
  auto quad = [&](short8 (&af)[4][2], short8 (&bf)[2][2], int io, int jo) {
    __builtin_amdgcn_s_setprio(1);
#pragma unroll
    for (int ks = 0; ks < 2; ++ks)
#pragma unroll
      for (int ip = 0; ip < 4; ++ip)
#pragma unroll
        for (int jp = 0; jp < 2; ++jp)
          acc[io + ip][jo + jp] = __builtin_amdgcn_mfma_f32_16x16x32_bf16(
              af[ip][ks], bf[jp][ks], acc[io + ip][jo + jp], 0, 0, 0);
    __builtin_amdgcn_s_setprio(0);
  };
  auto bar = [&]() {
    asm volatile("" ::: "memory");
    __builtin_amdgcn_s_barrier();
    asm volatile("" ::: "memory");
  };

  stgA(0, 0); stgB(0, 0); stgB(0, 1); stgA(0, 1);
  stgA(1, 0); stgB(1, 0); stgB(1, 1); stgA(1, 1);
  asm volatile("s_waitcnt vmcnt(8)" ::: "memory");
  bar();

  short8 a[4][2], b0[2][2], b1[2][2];
  for (int t = 0; t < NKT; ++t) {
    const u16* A0p = &As[t & 1][0][0];
    const u16* A1p = &As[t & 1][1][0];
    const u16* B0p = &Bs[t & 1][0][0];
    const u16* B1p = &Bs[t & 1][1][0];
    const bool pf = (t + 2 < NKT);
#pragma unroll
    for (int ip = 0; ip < 4; ++ip)
#pragma unroll
      for (int ks = 0; ks < 2; ++ks)
        a[ip][ks] = rdA(A0p, ip, ks);
#pragma unroll
    for (int jp = 0; jp < 2; ++jp)
#pragma unroll
      for (int ks = 0; ks < 2; ++ks)
        b0[jp][ks] = rdB(B0p, jp, ks);
    quad(a, b0, 0, 0);
    bar();
#pragma unroll
    for (int jp = 0; jp < 2; ++jp)
#pragma unroll
      for (int ks = 0; ks < 2; ++ks)
        b1[jp][ks] = rdB(B1p, jp, ks);
    if (pf) { stgA(t + 2, 0); stgB(t + 2, 0); }
    quad(a, b1, 0, 2);
    bar();
#pragma unroll
    for (int ip = 0; ip < 4; ++ip)
#pragma unroll
      for (int ks = 0; ks < 2; ++ks)
        a[ip][ks] = rdA(A1p, ip, ks);
    if (pf) stgB(t + 2, 1);
    quad(a, b0, 4, 0);
    bar();
    if (pf) stgA(t + 2, 1);
    if (t < NKT - 2)
      asm volatile("s_waitcnt vmcnt(8)" ::: "memory");
    else if (t == NKT - 2)
      asm volatile("s_waitcnt vmcnt(0)" ::: "memory");
    quad(a, b1, 4, 2);
    bar();
  }

  // epilogue: plain fp32 row-major store
#pragma unroll
  for (int i = 0; i < 8; ++i) {
    const int mb = row0 + wm * 128 + i * 16 + g * 4;
#pragma unroll
    for (int j = 0; j < 4; ++j) {
      const int n = col0 + wn * 64 + j * 16 + c;
#pragma unroll
      for (int r = 0; r < 4; ++r)
        out[(size_t)(mb + r) * DD + n] = acc[i][j][r];
    }
  }
}

// ------- causal flash attention (staged, software-pipelined dbuf) ----------
__global__ __launch_bounds__(256, 3) void k_attn(const u16* __restrict__ Q,
                                                 const u16* __restrict__ K,
                                                 const u16* __restrict__ Vt,
                                                 u16* __restrict__ O) {
  __shared__ __align__(16) u16 Kt[2][32 * 128];   // (kv, d) XOR-swizzled chunks
  __shared__ __align__(16) u16 Vs[2][128 * 32];   // (d, kv) XOR-swizzled chunks
  __shared__ __align__(16) u16 Pb[4 * 32 * 40];   // per-wave P (row, kv), stride 40
  const int tid = threadIdx.x;
  const int wave = tid >> 6, lane = tid & 63;
  const int c = lane & 15, g = lane >> 4;
  const int l = blockIdx.x;
  int qi, bh;
  if (l < 256) { qi = 8 + (l & 7); bh = l >> 3; }
  else         { qi = 7 - ((l - 256) & 7); bh = (l - 256) >> 3; }
  const int q0 = qi * 128;
  const u16* Qp = Q  + (size_t)bh * SS * HDD;
  const u16* Kp = K  + (size_t)bh * SS * HDD;
  const u16* Vp = Vt + (size_t)bh * SS * HDD;    // (HD,S)
  short8 qf[2][4];
#pragma unroll
  for (int ms = 0; ms < 2; ++ms)
#pragma unroll
    for (int kd = 0; kd < 4; ++kd)
      qf[ms][kd] = *reinterpret_cast<const short8*>(
          Qp + (size_t)(q0 + wave * 32 + ms * 16 + c) * HDD + kd * 32 + g * 8);
  f32x4 acc[2][8] = {};
  float psum[2][4] = {};
  const int ntiles = (qi + 1) * 4;               // kv tiles of 32 up to q0+128
  u16* pwav = Pb + wave * (32 * 40);
  const int krl = lane >> 4, kcl = lane & 15;    // K: 4 rows/instr, 16 chunks
  const int vrl = lane >> 2, vcl = lane & 3;     // V: 16 rows/instr, 4 chunks
  auto stage = [&](int t) {
    const int kv0 = t * 32;
    u16* kb = Kt[t & 1];
    u16* vb = Vs[t & 1];
#pragma unroll
    for (int j = 0; j < 2; ++j) {
      const int r0k = (j * 4 + wave) * 4;        // rows 0..31, step 4
      const int rowk = r0k + krl;
      gload16(Kp + (size_t)(kv0 + rowk) * HDD + ((kcl ^ (rowk & 15)) << 3),
              kb + r0k * 128);
      const int r0v = (j * 4 + wave) * 16;       // d-rows 0..127, step 16
      const int rowv = r0v + vrl;
      gload16(Vp + (size_t)rowv * SS + kv0 + ((vcl ^ (vrl & 3)) << 3),
              vb + r0v * 32);
    }
  };
  stage(0);
  for (int t = 0; t < ntiles; ++t) {
    __syncthreads();   // drains loads for tile t (issued a full tile ago)
    if (t + 1 < ntiles) stage(t + 1);
    const int kv0 = t * 32;
    const bool active = kv0 <= q0 + wave * 32 + 31;  // wave-uniform
    if (!active) continue;
    const u16* kb = Kt[t & 1];
    const u16* vv = Vs[t & 1];
    f32x4 s[2][2] = {};
#pragma unroll
    for (int ns = 0; ns < 2; ++ns)
#pragma unroll
      for (int kd = 0; kd < 4; ++kd) {
        const short8 b = *reinterpret_cast<const short8*>(
            kb + (ns * 16 + c) * 128 + (((kd * 4 + g) ^ c) << 3));
        s[0][ns] = __builtin_amdgcn_mfma_f32_16x16x32_bf16(qf[0][kd], b, s[0][ns], 0, 0, 0);
        s[1][ns] = __builtin_amdgcn_mfma_f32_16x16x32_bf16(qf[1][kd], b, s[1][ns], 0, 0, 0);
      }
#pragma unroll
    for (int ms = 0; ms < 2; ++ms) {
      const int qrow = q0 + wave * 32 + ms * 16 + g * 4;
#pragma unroll
      for (int r = 0; r < 4; ++r) {
        u16* pw = pwav + (ms * 16 + g * 4 + r) * 40 + c;
        float rs = 0.f;
#pragma unroll
        for (int ns = 0; ns < 2; ++ns) {
          const bool u = (kv0 + ns * 16 + c) <= (qrow + r);
          const float p = u ? __expf(s[ms][ns][r]) : 0.f;
          rs += p;
          pw[ns * 16] = f2bf(p);
        }
        psum[ms][r] += rs;
      }
    }
    short8 pa[2];
    pa[0] = *reinterpret_cast<const short8*>(pwav + c * 40 + g * 8);
    pa[1] = *reinterpret_cast<const short8*>(pwav + (16 + c) * 40 + g * 8);
#pragma unroll
    for (int nb = 0; nb < 8; ++nb) {
      const short8 vb2 = *reinterpret_cast<const short8*>(
          vv + (nb * 16 + c) * 32 + ((g ^ (c & 3)) << 3));
      acc[0][nb] = __builtin_amdgcn_mfma_f32_16x16x32_bf16(pa[0], vb2, acc[0][nb], 0, 0, 0);
      acc[1][nb] = __builtin_amdgcn_mfma_f32_16x16x32_bf16(pa[1], vb2, acc[1][nb], 0, 0, 0);
    }
  }
  const int b_ = bh >> 4, h_ = bh & 15;
#pragma unroll
  for (int ms = 0; ms < 2; ++ms) {
#pragma unroll
    for (int r = 0; r < 4; ++r) {
      float rs = psum[ms][r];
      rs += __shfl_xor(rs, 1);
      rs += __shfl_xor(rs, 2);
      rs += __shfl_xor(rs, 4);
      rs += __shfl_xor(rs, 8);
      const float inv = 1.f / rs;
      const int s_ = q0 + wave * 32 + ms * 16 + g * 4 + r;
      u16* op = O + ((size_t)(b_ * SS + s_)) * DD + h_ * HDD;
#pragma unroll
      for (int nb = 0; nb < 8; ++nb)
        op[nb * 16 + c] = f2bf(acc[ms][nb][r] * inv);
    }
  }
}

extern "C" void kernel_launch(void* const* d_in, const int* in_sizes, int n_in,
                              void* d_out, int out_size, void* d_ws, size_t ws_size,
                              hipStream_t stream) {
  const float* x  = (const float*)d_in[0];
  const float* fc = (const float*)d_in[1];
  const float* fs = (const float*)d_in[2];
  // d_in[3] = mask (unused; causal applied analytically)
  const float* wq = (const float*)d_in[4];
  const float* wk = (const float*)d_in[5];
  const float* wv = (const float*)d_in[6];
  const float* wo = (const float*)d_in[7];

  // workspace layout (bf16 elements)
  u16* ws  = (u16*)d_ws;
  u16* xb  = ws;                  // 4096x2048
  u16* wqt = xb  + 8388608;       // 2048x2048 each (N,K); wq/wk/wv contiguous
  u16* wot = wqt + 3 * 4194304;   // output-proj weight (N,K)
  u16* Qb  = wot + 4194304;       // section 0: Q (B,H,S,HD), RoPE'd+scaled
  u16* Kb  = Qb  + SEC;           // section 1: K (B,H,S,HD), RoPE'd
  u16* Vtb = Kb  + SEC;           // section 2: V transposed (B,H,HD,S)
  u16* ao  = Vtb + SEC;           // (B,S,DIM) attention output

  // prep: x conversion (z=4..7) + 4 weight transposes (z=0..3) in one launch
  k_prep<<<dim3(32, 32, 8), dim3(32, 8), 0, stream>>>(x, wq, wk, wv, wo, xb, wqt);
  // fused QKV projection + RoPE epilogue, 256^2 4-phase schedule (R2)
  k_qkv<<<384, 512, 0, stream>>>(xb, wqt, Qb, fc, fs);
  k_attn<<<512, 256, 0, stream>>>(Qb, Kb, Vtb, ao);
  // output projection: 256^2 4-phase (k_qkv clone), 128 blocks
  k_oproj<<<128, 512, 0, stream>>>(ao, wot, (float*)d_out);
}

// Round 10
// 407.885 us; speedup vs baseline: 1.0312x; 1.0208x over previous
//
#include <hip/hip_runtime.h>
#include <hip/hip_bf16.h>
#include <cstdint>
#include <cstddef>

// Problem constants
#define BB   2
#define SS   2048
#define DD   2048
#define HH   16
#define HDD  128
#define SEC  8388608   // B*H*S*HD elements per Q/K/V section
#define NKT  32        // K-tiles of 64 in DD=2048

typedef unsigned short u16;
typedef __attribute__((ext_vector_type(8))) short short8;   // 8 x bf16 (4 VGPRs)
typedef __attribute__((ext_vector_type(4))) float f32x4;    // MFMA 16x16 accumulator

__device__ __forceinline__ u16 f2bf(float f) {
  union { float f; uint32_t u; } v; v.f = f;
  uint32_t r = v.u + 0x7fffu + ((v.u >> 16) & 1u);  // RNE
  return (u16)(r >> 16);
}
__device__ __forceinline__ float bf2f(u16 b) {
  union { uint32_t u; float f; } v; v.u = ((uint32_t)b) << 16;
  return v.f;
}

// async global->LDS, 16B per lane; LDS dest = wave-uniform base + lane*16
__device__ __forceinline__ void gload16(const u16* g, u16* l) {
  __builtin_amdgcn_global_load_lds(
      (__attribute__((address_space(1))) void*)g,
      (__attribute__((address_space(3))) void*)l, 16, 0, 0);
}

// ------- prep: x fp32->bf16 (z>=4) + 4x weight transpose+convert (z<4) -----
__global__ void k_prep(const float* __restrict__ x,
                       const float* __restrict__ w0, const float* __restrict__ w1,
                       const float* __restrict__ w2, const float* __restrict__ w3,
                       u16* __restrict__ xb, u16* __restrict__ wt) {
  const int z = blockIdx.z;
  const int t = threadIdx.y * 32 + threadIdx.x;
  if (z >= 4) {  // convert x
    const int id = (z - 4) * 1024 + blockIdx.y * 32 + blockIdx.x;
    const size_t base = ((size_t)id * 256 + t) * 2;   // float4 units
    const float4* xv = reinterpret_cast<const float4*>(x);
    uint2* ov = reinterpret_cast<uint2*>(xb);
#pragma unroll
    for (int u = 0; u < 2; ++u) {
      const float4 v = xv[base + u];
      uint2 p;
      p.x = (uint32_t)f2bf(v.x) | ((uint32_t)f2bf(v.y) << 16);
      p.y = (uint32_t)f2bf(v.z) | ((uint32_t)f2bf(v.w) << 16);
      ov[base + u] = p;
    }
    return;
  }
  __shared__ float tls[64][65];
  const float* w = (z == 0) ? w0 : (z == 1) ? w1 : (z == 2) ? w2 : w3;
  u16* o = wt + (size_t)z * (DD * DD);
  const int n0 = blockIdx.x * 64, k0 = blockIdx.y * 64;
#pragma unroll
  for (int i = 0; i < 4; ++i) {
    const int f = t + 256 * i;            // float4 index in tile
    const int row = f >> 4, c4 = (f & 15) << 2;
    const float4 v = *reinterpret_cast<const float4*>(
        w + (size_t)(k0 + row) * DD + n0 + c4);
    tls[row][c4 + 0] = v.x; tls[row][c4 + 1] = v.y;
    tls[row][c4 + 2] = v.z; tls[row][c4 + 3] = v.w;
  }
  __syncthreads();
#pragma unroll
  for (int i = 0; i < 2; ++i) {
    const int nrow = (t >> 3) + 32 * i;
    const int kc8 = (t & 7) << 3;
    uint32_t pk[4];
#pragma unroll
    for (int jj = 0; jj < 4; ++jj) {
      const uint32_t lo = f2bf(tls[kc8 + 2 * jj][nrow]);
      const uint32_t hi = f2bf(tls[kc8 + 2 * jj + 1][nrow]);
      pk[jj] = lo | (hi << 16);
    }
    *reinterpret_cast<uint4*>(o + (size_t)(n0 + nrow) * DD + k0 + kc8) =
        make_uint4(pk[0], pk[1], pk[2], pk[3]);
  }
}

// ------- fused QKV GEMM: 256x256 tile, 4-phase/K-tile (T2+T4+T5) -----------
// R2 version (best measured: 133us, MfmaUtil 32, zero bank conflicts).
__global__ __launch_bounds__(512, 2) void k_qkv(const u16* __restrict__ A,
                                                const u16* __restrict__ Bt,
                                                u16* __restrict__ out,
                                                const float* __restrict__ fc,
                                                const float* __restrict__ fs) {
  __shared__ __align__(16) u16 As[2][2][128 * 64];
  __shared__ __align__(16) u16 Bs[2][2][128 * 64];
  const int tid = threadIdx.x;
  const int wave = tid >> 6, lane = tid & 63;
  const int c = lane & 15, g = lane >> 4;
  const int wm = wave >> 2, wn = wave & 3;
  const int x7 = c & 7;
  // XCD-aware swizzle (384 % 8 == 0 -> simple form is bijective)
  const int lb = blockIdx.x;
  const int wg = (lb & 7) * 48 + (lb >> 3);
  const int bx = wg / 24, by = wg % 24;
  const int row0 = bx * 256, col0 = by * 256;
  const int lr3 = lane >> 3;
  const int kch = ((lane & 7) ^ lr3) << 3;

  auto stgA = [&](int t, int h) {
    u16* dst = &As[t & 1][h][0];
#pragma unroll
    for (int u = 0; u < 2; ++u)
      gload16(A + (size_t)(row0 + u * 128 + h * 64 + wave * 8 + lr3) * DD + t * 64 + kch,
              dst + (u * 64 + wave * 8) * 64);
  };
  auto stgB = [&](int t, int h) {
    u16* dst = &Bs[t & 1][h][0];
#pragma unroll
    for (int u = 0; u < 2; ++u)
      gload16(Bt + (size_t)(col0 + u * 128 + wm * 64 + h * 32 + wn * 8 + lr3) * DD + t * 64 + kch,
              dst + (u * 64 + wave * 8) * 64);
  };
  auto rdA = [&](const u16* bp, int ip, int ks) {
    return *reinterpret_cast<const short8*>(
        bp + (wm * 64 + ip * 16 + c) * 64 + ((((ks << 2) | g) ^ x7) << 3));
  };
  auto rdB = [&](const u16* bp, int jp, int ks) {
    return *reinterpret_cast<const short8*>(
        bp + (wn * 32 + jp * 16 + c) * 64 + ((((ks << 2) | g) ^ x7) << 3));
  };

  f32x4 acc[8][4] = {};
  auto quad = [&](short8 (&af)[4][2], short8 (&bf)[2][2], int io, int jo) {
    __builtin_amdgcn_s_setprio(1);
#pragma unroll
    for (int ks = 0; ks < 2; ++ks)
#pragma unroll
      for (int ip = 0; ip < 4; ++ip)
#pragma unroll
        for (int jp = 0; jp < 2; ++jp)
          acc[io + ip][jo + jp] = __builtin_amdgcn_mfma_f32_16x16x32_bf16(
              af[ip][ks], bf[jp][ks], acc[io + ip][jo + jp], 0, 0, 0);
    __builtin_amdgcn_s_setprio(0);
  };
  auto bar = [&]() {
    asm volatile("" ::: "memory");
    __builtin_amdgcn_s_barrier();
    asm volatile("" ::: "memory");
  };

  // prologue: stage tiles 0 and 1 (8 vmem instr each), land tile 0
  stgA(0, 0); stgB(0, 0); stgB(0, 1); stgA(0, 1);
  stgA(1, 0); stgB(1, 0); stgB(1, 1); stgA(1, 1);
  asm volatile("s_waitcnt vmcnt(8)" ::: "memory");
  bar();

  short8 a[4][2], b0[2][2], b1[2][2];
  for (int t = 0; t < NKT; ++t) {
    const u16* A0p = &As[t & 1][0][0];
    const u16* A1p = &As[t & 1][1][0];
    const u16* B0p = &Bs[t & 1][0][0];
    const u16* B1p = &Bs[t & 1][1][0];
    const bool pf = (t + 2 < NKT);
    // ---- phase 1 (0,0): 12 ds_reads, no stage
#pragma unroll
    for (int ip = 0; ip < 4; ++ip)
#pragma unroll
      for (int ks = 0; ks < 2; ++ks)
        a[ip][ks] = rdA(A0p, ip, ks);
#pragma unroll
    for (int jp = 0; jp < 2; ++jp)
#pragma unroll
      for (int ks = 0; ks < 2; ++ks)
        b0[jp][ks] = rdB(B0p, jp, ks);
    quad(a, b0, 0, 0);
    bar();
    // ---- phase 2 (0,1): 4 ds_reads, stage A0/B0 of t+2 (dead since ph1)
#pragma unroll
    for (int jp = 0; jp < 2; ++jp)
#pragma unroll
      for (int ks = 0; ks < 2; ++ks)
        b1[jp][ks] = rdB(B1p, jp, ks);
    if (pf) { stgA(t + 2, 0); stgB(t + 2, 0); }
    quad(a, b1, 0, 2);
    bar();
    // ---- phase 3 (1,0): 8 ds_reads, stage B1 of t+2 (dead since ph2)
#pragma unroll
    for (int ip = 0; ip < 4; ++ip)
#pragma unroll
      for (int ks = 0; ks < 2; ++ks)
        a[ip][ks] = rdA(A1p, ip, ks);
    if (pf) stgB(t + 2, 1);
    quad(a, b0, 4, 0);
    bar();
    // ---- phase 4 (1,1): 0 ds_reads, stage A1 of t+2 (dead since ph3)
    if (pf) stgA(t + 2, 1);
    if (t < NKT - 2)
      asm volatile("s_waitcnt vmcnt(8)" ::: "memory");
    else if (t == NKT - 2)
      asm volatile("s_waitcnt vmcnt(0)" ::: "memory");
    quad(a, b1, 4, 2);
    bar();
  }

  // epilogue: D layout col=lane&15, row=(lane>>4)*4+reg (m89-verified)
  const int which = col0 >> 11;                    // block-uniform: 0=Q,1=K,2=V
#pragma unroll
  for (int i = 0; i < 8; ++i) {
    const int mb = row0 + wm * 128 + i * 16 + g * 4;
    const int b_ = mb >> 11, s0_ = mb & (SS - 1);
#pragma unroll
    for (int j = 0; j < 4; ++j) {
      const int n = col0 + wn * 64 + j * 16 + c;
      const int h_ = (n >> 7) & 15, d_ = n & (HDD - 1);
      if (which == 2) {
        ushort4 pk;
        pk.x = f2bf(acc[i][j][0]); pk.y = f2bf(acc[i][j][1]);
        pk.z = f2bf(acc[i][j][2]); pk.w = f2bf(acc[i][j][3]);
        *reinterpret_cast<ushort4*>(
            out + 2 * (size_t)SEC + (((size_t)(b_ * HH + h_)) * HDD + d_) * SS + s0_) = pk;
      } else {
        const int p = d_ >> 1;
        const bool ev = (d_ & 1) == 0;
        const float qsc = (which == 0) ? 0.08838834764831845f : 1.0f;
#pragma unroll
        for (int r = 0; r < 4; ++r) {
          const int s_ = s0_ + r;
          const float own = acc[i][j][r];
          const float par = __shfl_xor(own, 1);
          const float cv = fc[s_ * 64 + p], sv = fs[s_ * 64 + p];
          const float ro = ev ? (own * cv - par * sv) : (par * sv + own * cv);
          out[(size_t)which * SEC + (((size_t)(b_ * HH + h_)) * SS + s_) * HDD + d_] =
              f2bf(ro * qsc);
        }
      }
    }
  }
}

// ------- output projection: 256x256 tile, 4-phase (k_qkv clone) ------------
__global__ __launch_bounds__(512, 2) void k_oproj(const u16* __restrict__ A,
                                                  const u16* __restrict__ Bt,
                                                  float* __restrict__ out) {
  __shared__ __align__(16) u16 As[2][2][128 * 64];
  __shared__ __align__(16) u16 Bs[2][2][128 * 64];
  const int tid = threadIdx.x;
  const int wave = tid >> 6, lane = tid & 63;
  const int c = lane & 15, g = lane >> 4;
  const int wm = wave >> 2, wn = wave & 3;
  const int x7 = c & 7;
  // XCD-aware swizzle (128 % 8 == 0 -> bijective)
  const int lb = blockIdx.x;
  const int wg = (lb & 7) * 16 + (lb >> 3);
  const int bx = wg >> 3, by = wg & 7;
  const int row0 = bx * 256, col0 = by * 256;
  const int lr3 = lane >> 3;
  const int kch = ((lane & 7) ^ lr3) << 3;

  auto stgA = [&](int t, int h) {
    u16* dst = &As[t & 1][h][0];
#pragma unroll
    for (int u = 0; u < 2; ++u)
      gload16(A + (size_t)(row0 + u * 128 + h * 64 + wave * 8 + lr3) * DD + t * 64 + kch,
              dst + (u * 64 + wave * 8) * 64);
  };
  auto stgB = [&](int t, int h) {
    u16* dst = &Bs[t & 1][h][0];
#pragma unroll
    for (int u = 0; u < 2; ++u)
      gload16(Bt + (size_t)(col0 + u * 128 + wm * 64 + h * 32 + wn * 8 + lr3) * DD + t * 64 + kch,
              dst + (u * 64 + wave * 8) * 64);
  };
  auto rdA = [&](const u16* bp, int ip, int ks) {
    return *reinterpret_cast<const short8*>(
        bp + (wm * 64 + ip * 16 + c) * 64 + ((((ks << 2) | g) ^ x7) << 3));
  };
  auto rdB = [&](const u16* bp, int jp, int ks) {
    return *reinterpret_cast<const short8*>(
        bp + (wn * 32 + jp * 16 + c) * 64 + ((((ks << 2) | g) ^ x7) << 3));
  };

  f32x4 acc[8][4] = {};
  auto quad = [&](short8 (&af)[4][2], short8 (&bf)[2][2], int io, int jo) {
    __builtin_amdgcn_s_setprio(1);
#pragma unroll
    for (int ks = 0; ks < 2; ++ks)
#pragma unroll
      for (int ip = 0; ip < 4; ++ip)
#pragma unroll
        for (int jp = 0; jp < 2; ++jp)
          acc[io + ip][jo + jp] = __builtin_amdgcn_mfma_f32_16x16x32_bf16(
              af[ip][ks], bf[jp][ks], acc[io + ip][jo + jp], 0, 0, 0);
    __builtin_amdgcn_s_setprio(0);
  };
  auto bar = [&]() {
    asm volatile("" ::: "memory");
    __builtin_amdgcn_s_barrier();
    asm volatile("" ::: "memory");
  };

  stgA(0, 0); stgB(0, 0); stgB(0, 1); stgA(0, 1);
  stgA(1, 0); stgB(1, 0); stgB(1, 1); stgA(1, 1);
  asm volatile("s_waitcnt vmcnt(8)" ::: "memory");
  bar();

  short8 a[4][2], b0[2][2], b1[2][2];
  for (int t = 0; t < NKT; ++t) {
    const u16* A0p = &As[t & 1][0][0];
    const u16* A1p = &As[t & 1][1][0];
    const u16* B0p = &Bs[t & 1][0][0];
    const u16* B1p = &Bs[t & 1][1][0];
    const bool pf = (t + 2 < NKT);
#pragma unroll
    for (int ip = 0; ip < 4; ++ip)
#pragma unroll
      for (int ks = 0; ks < 2; ++ks)
        a[ip][ks] = rdA(A0p, ip, ks);
#pragma unroll
    for (int jp = 0; jp < 2; ++jp)
#pragma unroll
      for (int ks = 0; ks < 2; ++ks)
        b0[jp][ks] = rdB(B0p, jp, ks);
    quad(a, b0, 0, 0);
    bar();
#pragma unroll
    for (int jp = 0; jp < 2; ++jp)
#pragma unroll
      for (int ks = 0; ks < 2; ++ks)
        b1[jp][ks] = rdB(B1p, jp, ks);
    if (pf) { stgA(t + 2, 0); stgB(t + 2, 0); }
    quad(a, b1, 0, 2);
    bar();
#pragma unroll
    for (int ip = 0; ip < 4; ++ip)
#pragma unroll
      for (int ks = 0; ks < 2; ++ks)
        a[ip][ks] = rdA(A1p, ip, ks);
    if (pf) stgB(t + 2, 1);
    quad(a, b0, 4, 0);
    bar();
    if (pf) stgA(t + 2, 1);
    if (t < NKT - 2)
      asm volatile("s_waitcnt vmcnt(8)" ::: "memory");
    else if (t == NKT - 2)
      asm volatile("s_waitcnt vmcnt(0)" ::: "memory");
    quad(a, b1, 4, 2);
    bar();
  }

#pragma unroll
  for (int i = 0; i < 8; ++i) {
    const int mb = row0 + wm * 128 + i * 16 + g * 4;
#pragma unroll
    for (int j = 0; j < 4; ++j) {
      const int n = col0 + wn * 64 + j * 16 + c;
#pragma unroll
      for (int r = 0; r < 4; ++r)
        out[(size_t)(mb + r) * DD + n] = acc[i][j][r];
    }
  }
}

// ------- causal flash attention (R10: 8-wave paired blocks) ----------------
// 256 blocks = 32 bh x 8 pair-slots, ONE block per CU. Waves 0-3 compute
// q-tile 8+j, waves 4-7 q-tile 7-j of the SAME bh -> per-block compute is
// exactly uniform (qi_hi + qi_lo = 15). K/V for the pair is staged ONCE
// (previously the hi and lo blocks each staged the same KV stream: 2x the
// fetch + 2x the staging instructions). Staging split across 8 waves
// (1 K + 1 V gload16/wave/tile). Same both-sides XOR swizzles (K key
// row&15 -> read ^c; V key row&3 -> read ^(c&3); r0v=w*16 keeps key
// alignment). Per-wave softmax/PV/epilogue unchanged. LDS 52 KB.
// bh-clustered decode: a bh's 8 blocks share raw&7 -> same XCD L2 for K/V.
__global__ __launch_bounds__(512) void k_attn(const u16* __restrict__ Q,
                                              const u16* __restrict__ K,
                                              const u16* __restrict__ Vt,
                                              u16* __restrict__ O) {
  __shared__ __align__(16) u16 Kt[2][32 * 128];   // (kv, d) XOR-swizzled chunks
  __shared__ __align__(16) u16 Vs[2][128 * 32];   // (d, kv) XOR-swizzled chunks
  __shared__ __align__(16) u16 Pb[8 * 32 * 40];   // per-wave P (row, kv), stride 40
  const int tid = threadIdx.x;
  const int wave = tid >> 6, lane = tid & 63;
  const int c = lane & 15, g = lane >> 4;
  // decode: bh from raw bits [0:4] (raw&7 -> XCD cluster), pair-slot j from [5:7]
  const int raw = blockIdx.x;
  const int bh = (raw & 7) | (((raw >> 3) & 3) << 3);
  const int j = raw >> 5;
  const int qi_hi = 8 + j, qi_lo = 7 - j;
  const int qrow_base = ((wave < 4) ? qi_hi * 128 : qi_lo * 128) + (wave & 3) * 32;
  const u16* Qp = Q  + (size_t)bh * SS * HDD;
  const u16* Kp = K  + (size_t)bh * SS * HDD;
  const u16* Vp = Vt + (size_t)bh * SS * HDD;    // (HD,S)
  // preload Q A-frags: rows qrow_base + ms*16 + c, k = kd*32 + g*8
  short8 qf[2][4];
#pragma unroll
  for (int ms = 0; ms < 2; ++ms)
#pragma unroll
    for (int kd = 0; kd < 4; ++kd)
      qf[ms][kd] = *reinterpret_cast<const short8*>(
          Qp + (size_t)(qrow_base + ms * 16 + c) * HDD + kd * 32 + g * 8);
  f32x4 acc[2][8] = {};
  float psum[2][4] = {};
  const int ntiles = (qi_hi + 1) * 4;            // loop bound = hi range
  const int lastact = qrow_base >> 5;            // active while t <= lastact
  u16* pwav = Pb + wave * (32 * 40);
  const int krl = lane >> 4, kcl = lane & 15;    // K: 4 rows/instr, 16 chunks
  const int vrl = lane >> 2, vcl = lane & 3;     // V: 16 rows/instr, 4 chunks
  auto stage = [&](int t) {
    const int kv0 = t * 32;
    u16* kb = Kt[t & 1];
    u16* vb = Vs[t & 1];
    // 8 waves split the 32 K-rows (4 each) and 128 V-d-rows (16 each)
    const int r0k = wave * 4;
    const int rowk = r0k + krl;
    gload16(Kp + (size_t)(kv0 + rowk) * HDD + ((kcl ^ (rowk & 15)) << 3),
            kb + r0k * 128);
    const int r0v = wave * 16;
    const int rowv = r0v + vrl;
    gload16(Vp + (size_t)rowv * SS + kv0 + ((vcl ^ (vrl & 3)) << 3),
            vb + r0v * 32);
  };
  stage(0);
  for (int t = 0; t < ntiles; ++t) {
    __syncthreads();   // drains loads for tile t (issued a full tile ago);
                       // also fences buffer reuse for tile t+1's staging
    if (t + 1 < ntiles) stage(t + 1);
    const int kv0 = t * 32;
    const bool active = t <= lastact;             // wave-uniform
    if (!active) continue;
    const u16* kb = Kt[t & 1];
    const u16* vv = Vs[t & 1];
    f32x4 s[2][2] = {};
#pragma unroll
    for (int ns = 0; ns < 2; ++ns)
#pragma unroll
      for (int kd = 0; kd < 4; ++kd) {
        const short8 b = *reinterpret_cast<const short8*>(
            kb + (ns * 16 + c) * 128 + (((kd * 4 + g) ^ c) << 3));
        s[0][ns] = __builtin_amdgcn_mfma_f32_16x16x32_bf16(qf[0][kd], b, s[0][ns], 0, 0, 0);
        s[1][ns] = __builtin_amdgcn_mfma_f32_16x16x32_bf16(qf[1][kd], b, s[1][ns], 0, 0, 0);
      }
#pragma unroll
    for (int ms = 0; ms < 2; ++ms) {
      const int qrow = qrow_base + ms * 16 + g * 4;
#pragma unroll
      for (int r = 0; r < 4; ++r) {
        u16* pw = pwav + (ms * 16 + g * 4 + r) * 40 + c;
        float rs = 0.f;
#pragma unroll
        for (int ns = 0; ns < 2; ++ns) {
          const bool u = (kv0 + ns * 16 + c) <= (qrow + r);
          const float p = u ? __expf(s[ms][ns][r]) : 0.f;
          rs += p;
          pw[ns * 16] = f2bf(p);
        }
        psum[ms][r] += rs;
      }
    }
    short8 pa[2];
    pa[0] = *reinterpret_cast<const short8*>(pwav + c * 40 + g * 8);
    pa[1] = *reinterpret_cast<const short8*>(pwav + (16 + c) * 40 + g * 8);
#pragma unroll
    for (int nb = 0; nb < 8; ++nb) {
      const short8 vb2 = *reinterpret_cast<const short8*>(
          vv + (nb * 16 + c) * 32 + ((g ^ (c & 3)) << 3));
      acc[0][nb] = __builtin_amdgcn_mfma_f32_16x16x32_bf16(pa[0], vb2, acc[0][nb], 0, 0, 0);
      acc[1][nb] = __builtin_amdgcn_mfma_f32_16x16x32_bf16(pa[1], vb2, acc[1][nb], 0, 0, 0);
    }
  }
  const int b_ = bh >> 4, h_ = bh & 15;
#pragma unroll
  for (int ms = 0; ms < 2; ++ms) {
#pragma unroll
    for (int r = 0; r < 4; ++r) {
      float rs = psum[ms][r];
      rs += __shfl_xor(rs, 1);
      rs += __shfl_xor(rs, 2);
      rs += __shfl_xor(rs, 4);
      rs += __shfl_xor(rs, 8);
      const float inv = 1.f / rs;
      const int s_ = qrow_base + ms * 16 + g * 4 + r;
      u16* op = O + ((size_t)(b_ * SS + s_)) * DD + h_ * HDD;
#pragma unroll
      for (int nb = 0; nb < 8; ++nb)
        op[nb * 16 + c] = f2bf(acc[ms][nb][r] * inv);
    }
  }
}

extern "C" void kernel_launch(void* const* d_in, const int* in_sizes, int n_in,
                              void* d_out, int out_size, void* d_ws, size_t ws_size,
                              hipStream_t stream) {
  const float* x  = (const float*)d_in[0];
  const float* fc = (const float*)d_in[1];
  const float* fs = (const float*)d_in[2];
  // d_in[3] = mask (unused; causal applied analytically)
  const float* wq = (const float*)d_in[4];
  const float* wk = (const float*)d_in[5];
  const float* wv = (const float*)d_in[6];
  const float* wo = (const float*)d_in[7];

  // workspace layout (bf16 elements)
  u16* ws  = (u16*)d_ws;
  u16* xb  = ws;                  // 4096x2048
  u16* wqt = xb  + 8388608;       // 2048x2048 each (N,K); wq/wk/wv contiguous
  u16* wot = wqt + 3 * 4194304;   // output-proj weight (N,K)
  u16* Qb  = wot + 4194304;       // section 0: Q (B,H,S,HD), RoPE'd+scaled
  u16* Kb  = Qb  + SEC;           // section 1: K (B,H,S,HD), RoPE'd
  u16* Vtb = Kb  + SEC;           // section 2: V transposed (B,H,HD,S)
  u16* ao  = Vtb + SEC;           // (B,S,DIM) attention output

  // prep: x conversion (z=4..7) + 4 weight transposes (z=0..3) in one launch
  k_prep<<<dim3(32, 32, 8), dim3(32, 8), 0, stream>>>(x, wq, wk, wv, wo, xb, wqt);
  // fused QKV projection + RoPE epilogue, 256^2 4-phase schedule (R2)
  k_qkv<<<384, 512, 0, stream>>>(xb, wqt, Qb, fc, fs);
  // attention: 256 paired 8-wave blocks (KV staged once per pair)
  k_attn<<<256, 512, 0, stream>>>(Qb, Kb, Vtb, ao);
  // output projection: 256^2 4-phase (k_qkv clone), 128 blocks
  k_oproj<<<128, 512, 0, stream>>>(ao, wot, (float*)d_out);
}